// Round 3
// baseline (608.113 us; speedup 1.0000x reference)
//
#include <hip/hip_runtime.h>
#include <stdint.h>

#define BATCH 16
#define CDIM 64
#define NDIM 65536
#define EPSV 1e-6f

typedef __attribute__((ext_vector_type(8))) _Float16 f16x8;
typedef __attribute__((ext_vector_type(4))) float f32x4;
typedef __attribute__((ext_vector_type(4))) uint32_t u32x4;
typedef __attribute__((ext_vector_type(4))) short s16x4;

static __device__ __forceinline__ short h2s(_Float16 h) {
    return (short)__builtin_bit_cast(unsigned short, h);
}
static __device__ __forceinline__ _Float16 s2h(short s) {
    return __builtin_bit_cast(_Float16, (unsigned short)s);
}
static __device__ __forceinline__ unsigned short h2u(_Float16 h) {
    return __builtin_bit_cast(unsigned short, h);
}

// ---------------- Kernel 1: Gram partials + tvec partials + persist raw u ----------------
// grid 1024 = 16 batches x 64 tiles; each block: 4 chunks of 256 positions.
// Phase A: lean x-load (no register store-buffer -> deep load pipelining),
//          per-position ss/cs, fp16 cvt, ds_write_b16 into [c][n] tile.
// Phase B: MFMA Gram with inv[n] riding the A-fragment; 5th MFMA = tvec.
// Phase C: LDS transpose copy -> ut[n][c] with COALESCED b128 row stores
//          (ds_read2_b32 2x2 tiles + v_perm hi/lo split; banks 2-way free).
#define T1 256
#define P1 264   // fp16 row pitch; 528 B rows, 16B-aligned b128 frags
#define CHUNKS 4
#define NTILE1 64

__global__ __launch_bounds__(256, 4)
void gram_kernel(const float* __restrict__ x, float* __restrict__ pmat,
                 float* __restrict__ pt, short* __restrict__ ut,
                 float2* __restrict__ meta) {
    __shared__ __align__(16) short ldsU[CDIM][P1];          // raw fp16 v, [c][n]
    __shared__ __align__(16) unsigned short ldsI[T1];       // fp16 inv[n]
    __shared__ __align__(16) unsigned short ldsGk[T1];      // fp16 (inv*cs)[n]

    const int tid = threadIdx.x;
    const int b = blockIdx.x >> 6;
    const int tileIdx = blockIdx.x & 63;
    const int w = tid >> 6;
    const int lane = tid & 63;
    const int cq = lane >> 4;
    const int cr = lane & 15;

    f32x4 acc0 = {0.f, 0.f, 0.f, 0.f};
    f32x4 acc1 = acc0, acc2 = acc0, acc3 = acc0, acct = acc0;

    const float* xbase = x + (size_t)b * CDIM * NDIM;

    for (int chunk = 0; chunk < CHUNKS; ++chunk) {
        const int nc0 = tileIdx * (T1 * CHUNKS) + chunk * T1;
        const int n = nc0 + tid;                // thread owns one position
        const float* xb = xbase + n;

        // ---- Phase A: load x column, sums, cvt, LDS write (no reg buffer) ----
        float ss = 0.f, cs = 0.f;
#pragma unroll
        for (int c = 0; c < CDIM; ++c) {
            float v = __builtin_nontemporal_load(xb + (size_t)c * NDIM);
            ss += v * v;
            cs += v;
            ldsU[c][tid] = h2s((_Float16)v);
        }
        const float inv = 1.f / (sqrtf(ss) + EPSV);
        meta[(size_t)b * NDIM + n] = make_float2(cs, inv);
        ldsI[tid] = h2u((_Float16)inv);
        ldsGk[tid] = h2u((_Float16)(inv * cs));
        __syncthreads();

        // ---- Phase C: transpose copy LDS[c][n] -> ut[n][c], coalesced b128 ----
        // thread pair-task: rows (2*np, 2*np+1), channels c0..c0+7.
        {
            short* utb = ut + ((size_t)b * NDIM + nc0) * CDIM;
            const int np = tid & 127;
#pragma unroll
            for (int it = 0; it < 4; ++it) {
                const int c0 = ((tid >> 7) + 2 * it) * 8;
                uint32_t dw[8];
#pragma unroll
                for (int k = 0; k < 4; ++k) {
                    dw[2 * k] = *(const uint32_t*)&ldsU[c0 + 2 * k][2 * np];
                    dw[2 * k + 1] = *(const uint32_t*)&ldsU[c0 + 2 * k + 1][2 * np];
                }
                uint32_t lo[4], hi[4];
#pragma unroll
                for (int k = 0; k < 4; ++k) {
                    lo[k] = __builtin_amdgcn_perm(dw[2 * k + 1], dw[2 * k], 0x05040100u);
                    hi[k] = __builtin_amdgcn_perm(dw[2 * k + 1], dw[2 * k], 0x07060302u);
                }
                short* r0 = utb + (size_t)(2 * np) * CDIM + c0;
                *(u32x4*)r0 = (u32x4){lo[0], lo[1], lo[2], lo[3]};
                *(u32x4*)(r0 + CDIM) = (u32x4){hi[0], hi[1], hi[2], hi[3]};
            }
        }

        // ---- Phase B: MFMA Gram; A-frag carries inv[k]; 5th MFMA = tvec ----
#pragma unroll
        for (int ks = 0; ks < 8; ++ks) {
            const int k0 = ks * 32 + cq * 8;
            f16x8 araw = *(const f16x8*)&ldsU[w * 16 + cr][k0];
            f16x8 ipk = *(const f16x8*)&ldsI[k0];
            f16x8 ascl = araw * ipk;            // 4x v_pk_mul_f16
            f16x8 b0 = *(const f16x8*)&ldsU[cr][k0];
            f16x8 b1 = *(const f16x8*)&ldsU[16 + cr][k0];
            f16x8 b2 = *(const f16x8*)&ldsU[32 + cr][k0];
            f16x8 b3 = *(const f16x8*)&ldsU[48 + cr][k0];
            acc0 = __builtin_amdgcn_mfma_f32_16x16x32_f16(ascl, b0, acc0, 0, 0, 0);
            acc1 = __builtin_amdgcn_mfma_f32_16x16x32_f16(ascl, b1, acc1, 0, 0, 0);
            acc2 = __builtin_amdgcn_mfma_f32_16x16x32_f16(ascl, b2, acc2, 0, 0, 0);
            acc3 = __builtin_amdgcn_mfma_f32_16x16x32_f16(ascl, b3, acc3, 0, 0, 0);
            f16x8 gk = *(const f16x8*)&ldsGk[k0];
            f16x8 bt = (cr == 0) ? gk : (f16x8)(_Float16)0.f;
            acct = __builtin_amdgcn_mfma_f32_16x16x32_f16(ascl, bt, acct, 0, 0, 0);
        }
        __syncthreads();
    }
    // tvec partial: D[row][0] lives in cr==0 lanes, rows = w*16 + cq*4 + r
    if (cr == 0) {
        float* ptb = pt + (size_t)blockIdx.x * CDIM + w * 16 + cq * 4;
#pragma unroll
        for (int r = 0; r < 4; ++r) ptb[r] = acct[r];
    }
    // emit Gram partial: C/D layout col=lane&15, row=quad*4+reg
    float* pm = pmat + (size_t)blockIdx.x * CDIM * CDIM;
    const f32x4 accs[4] = {acc0, acc1, acc2, acc3};
#pragma unroll
    for (int mt = 0; mt < 4; ++mt) {
#pragma unroll
        for (int r = 0; r < 4; ++r) {
            const int row = w * 16 + cq * 4 + r;
            const int col = mt * 16 + cr;
            pm[row * CDIM + col] = accs[mt][r];
        }
    }
}

// ---------------- Kernel 1.5: reduce partials -> matb (fp16), tailor ----------------
__global__ __launch_bounds__(256, 4)
void reduce_kernel(const float* __restrict__ pmat, const float* __restrict__ pt,
                   short* __restrict__ matb, float* __restrict__ tl) {
    const int blk = blockIdx.x;
    const int tid = threadIdx.x;
    if (blk < 256) {            // mat: 16 batches x 4096 elems
        const int b = blk >> 4;
        const int o = (blk & 15) * 256 + tid;
        float s = 0.f;
#pragma unroll 8
        for (int t = 0; t < NTILE1; ++t)
            s += __builtin_nontemporal_load(
                &pmat[((size_t)(b * NTILE1 + t)) * (CDIM * CDIM) + o]);
        matb[(size_t)b * CDIM * CDIM + o] = h2s((_Float16)s);
    } else {                    // tailor: 16 x 64
        const int idx = (blk - 256) * 256 + tid;
        const int b = idx >> 6;
        const int c = idx & 63;
        float s = 0.f;
#pragma unroll 8
        for (int t = 0; t < NTILE1; ++t)
            s += __builtin_nontemporal_load(&pt[(size_t)(b * NTILE1 + t) * CDIM + c]);
        tl[idx] = 1.f / ((float)NDIM + s + EPSV);
    }
}

// ---------------- Kernel 2: matvec + fused epilogue, no x re-read ----------------
// ut holds raw fp16 x: bfrag = raw row, epilogue residual = raw value, and the
// per-position normalization enters only as invn * acc.
#define PM 72    // matrix fp16 pitch: 144 B rows, 16B-aligned b128 frags

__global__ __launch_bounds__(256, 4)
void out_kernel(const short* __restrict__ ut, const short* __restrict__ matb,
                const float* __restrict__ tl, const float2* __restrict__ meta,
                const float* __restrict__ gamma, float* __restrict__ out) {
    __shared__ __align__(16) short ldsM[CDIM][PM];
    __shared__ float ldsTL[CDIM];

    const int tid = threadIdx.x;
    const int bid = (int)(gridDim.x - 1 - blockIdx.x);
    const int b = bid >> 8;
    const int n0 = (bid & 255) * 256;
    const int w = tid >> 6;
    const int lane = tid & 63;
    const int cq = lane >> 4;
    const int cr = lane & 15;

    // stage matrix (fp16, 8 KB) + tailor
    {
        const short* mb = matb + (size_t)b * CDIM * CDIM;
        const int c = tid >> 2;
        const int seg = (tid & 3) * 16;
        u32x4 q0 = *(const u32x4*)(mb + c * CDIM + seg);
        u32x4 q1 = *(const u32x4*)(mb + c * CDIM + seg + 8);
        *(u32x4*)&ldsM[c][seg] = q0;
        *(u32x4*)&ldsM[c][seg + 8] = q1;
    }
    if (tid < CDIM) ldsTL[tid] = tl[b * CDIM + tid];
    __syncthreads();

    // A-frags from matrix: A[c][k=m]
    f16x8 afrag[4][2];
#pragma unroll
    for (int ct = 0; ct < 4; ++ct)
#pragma unroll
        for (int ks = 0; ks < 2; ++ks)
            afrag[ct][ks] = *(const f16x8*)&ldsM[ct * 16 + cr][ks * 32 + cq * 8];

    f32x4 acc[4][4];
#pragma unroll
    for (int p = 0; p < 4; ++p)
#pragma unroll
        for (int ct = 0; ct < 4; ++ct)
            acc[p][ct] = (f32x4){0.f, 0.f, 0.f, 0.f};

    const short* ub = ut + (size_t)b * NDIM * CDIM;

    // D(64 x 256) = M(64x64) @ U^T; wave w handles pos-tiles 4w..4w+3
#pragma unroll
    for (int p = 0; p < 4; ++p) {
        const int n = n0 + (w * 4 + p) * 16 + cr;
        const short* urow = ub + (size_t)n * CDIM;
#pragma unroll
        for (int ks = 0; ks < 2; ++ks) {
            f16x8 bfrag = *(const f16x8*)(urow + ks * 32 + cq * 8);
#pragma unroll
            for (int ct = 0; ct < 4; ++ct)
                acc[p][ct] = __builtin_amdgcn_mfma_f32_16x16x32_f16(
                    afrag[ct][ks], bfrag, acc[p][ct], 0, 0, 0);
        }
    }

    // epilogue: out = v + gamma * tl[c] * (cs[n] + inv[n]*y[c,n])
    const float g = gamma[0];
    float* obase = out + (size_t)b * CDIM * NDIM;
#pragma unroll
    for (int p = 0; p < 4; ++p) {
        const int n = n0 + (w * 4 + p) * 16 + cr;
        const float2 ms = meta[(size_t)b * NDIM + n];
        const float csn = ms.x;
        const float invn = ms.y;
        const short* urow = ub + (size_t)n * CDIM;
#pragma unroll
        for (int ct = 0; ct < 4; ++ct) {
            const int c0 = ct * 16 + cq * 4;
            s16x4 uv = *(const s16x4*)(urow + c0);
#pragma unroll
            for (int r = 0; r < 4; ++r) {
                const int c = c0 + r;
                float val = (float)s2h(uv[r]) +
                            g * ldsTL[c] * (csn + invn * acc[p][ct][r]);
                __builtin_nontemporal_store(val, obase + (size_t)c * NDIM + n);
            }
        }
    }
}

extern "C" void kernel_launch(void* const* d_in, const int* in_sizes, int n_in,
                              void* d_out, int out_size, void* d_ws, size_t ws_size,
                              hipStream_t stream) {
    const float* x = (const float*)d_in[0];
    const float* gamma = (const float*)d_in[1];
    float* out = (float*)d_out;
    // workspace layout (f32 slots):
    float* ws = (float*)d_ws;
    short* ut = (short*)ws;                                   // 16*65536*64 fp16 = 128 MB
    float* pmat = ws + (size_t)33554432;                      // 1024 x 4096 f32
    float* pt = pmat + (size_t)1024 * CDIM * CDIM;            // 1024 x 64 f32
    float2* meta = (float2*)(pt + (size_t)1024 * CDIM);       // 16 x 65536 float2
    short* matb = (short*)((float*)meta + (size_t)2 * BATCH * NDIM); // 16 x 4096 fp16
    float* tl = (float*)(matb + (size_t)BATCH * CDIM * CDIM); // 16 x 64 f32

    hipLaunchKernelGGL(gram_kernel, dim3(BATCH * NTILE1), dim3(256), 0, stream,
                       x, pmat, pt, ut, meta);
    hipLaunchKernelGGL(reduce_kernel, dim3(260), dim3(256), 0, stream,
                       pmat, pt, matb, tl);
    hipLaunchKernelGGL(out_kernel, dim3(BATCH * 256), dim3(256), 0, stream,
                       ut, matb, tl, meta, gamma, out);
}